// Round 9
// baseline (992.325 us; speedup 1.0000x reference)
//
#include <hip/hip_runtime.h>
#include <hip/hip_bf16.h>

typedef float f32x4 __attribute__((ext_vector_type(4)));
typedef short bf16x8 __attribute__((ext_vector_type(8)));

#define HH 512
#define WW 512
#define NPLANES 48              // B*C = 16*3
#define TILE 32
#define HALO 11
#define KSIZE 23
#define NBLK (16 * 16 * NPLANES)
#define C1V 1.0e-4f             // 0.01^2
#define C2V 9.0e-4f             // 0.03^2

// LDS layout (ushort indices). Overflow reads of padded M-rows (54..63):
// sB rows 54..63 -> sA rows 0..9 (finite staged bf16); sA rows 54..63 ->
// G region (finite bf16 taps). All junk multiplied by exact zeros in G.
#define SB_O   0                // 54 rows * 72
#define SA_O   3888             // 54 rows * 72
#define G_O    7776             // 32 rows * 64, xor-swizzled
#define HB_O   9824             // 5 ch * 32 cols * 64, xor-swizzled
#define HB_CH  2048
#define SPITCH 72               // staging pitch (16B-aligned rows, bank-spread)
#define LDS_TOT 20064           // 40128 B -> 4 blocks/CU

// XOR bank swizzle for pitch-64 regions; preserves 16B blocks (bits 0..2).
#define SWZ(rho, k) ((k) ^ (((rho) & 7) << 3))

__device__ __forceinline__ unsigned f2bf(float x) {   // fp32 -> bf16 bits (RNE)
    unsigned u = __float_as_uint(x);
    return (u + 0x7fffu + ((u >> 16) & 1u)) >> 16;
}

// pack two fp32 -> bf16 pair (lo = a, hi = b), RNE (v_cvt_pk_bf16_f32)
__device__ __forceinline__ unsigned cvtpk(float a, float b) {
    union { __hip_bfloat162 h; unsigned u; } cv;
    cv.h = __float22bfloat162_rn(make_float2(a, b));
    return cv.u;
}

// elementwise bf16 product of two bf16-pair dwords (fp32 exact mul, RNE round)
__device__ __forceinline__ unsigned bfmul2(unsigned a, unsigned b) {
    float al = __uint_as_float(a << 16), ah = __uint_as_float(a & 0xffff0000u);
    float bl = __uint_as_float(b << 16), bh = __uint_as_float(b & 0xffff0000u);
    return cvtpk(al * bl, ah * bh);
}

__device__ __forceinline__ uint4 bfmul4(uint4 a, uint4 b) {
    uint4 r;
    r.x = bfmul2(a.x, b.x); r.y = bfmul2(a.y, b.y);
    r.z = bfmul2(a.z, b.z); r.w = bfmul2(a.w, b.w);
    return r;
}

__device__ __forceinline__ f32x4 mfma16(uint4 a, uint4 b, f32x4 c) {
    union { uint4 u; bf16x8 h; } ua, ub;
    ua.u = a; ub.u = b;
    return __builtin_amdgcn_mfma_f32_16x16x32_bf16(ua.h, ub.h, c, 0, 0, 0);
}

// Build G[32][64] bf16 (row-major, plain): G[r][k] = g[k-r] for 0<=k-r<23 else 0.
__global__ void ssim_prep_kernel(const float* __restrict__ w, unsigned short* __restrict__ G) {
    __shared__ float sg[KSIZE];
    const int tid = threadIdx.x;
    if (tid < KSIZE) {
        float s = 0.f;
        #pragma unroll
        for (int k = 0; k < KSIZE; ++k) s += w[tid * KSIZE + k];
        sg[tid] = s;     // 1D taps = row sums of separable normalized 2D kernel (exact)
    }
    __syncthreads();
    for (int t = tid; t < 32 * 64; t += 256) {
        int r = t >> 6, k = t & 63, d = k - r;
        unsigned short v = 0;
        if (d >= 0 && d < KSIZE) v = (unsigned short)f2bf(sg[d]);
        G[t] = v;
    }
}

__global__ __launch_bounds__(256, 4) void ssim_main_kernel(
    const float* __restrict__ in, const float* __restrict__ tg,
    const unsigned short* __restrict__ G,
    float* __restrict__ acc, unsigned* __restrict__ cnt, float* __restrict__ out)
{
    __shared__ __align__(16) unsigned short lds[LDS_TOT];
    __shared__ float swsum[4];

    const int tid = threadIdx.x;
    const int wave = tid >> 6, lane = tid & 63;
    const int m = lane & 15, q = lane >> 4;

    const int blk = blockIdx.x;
    const int plane = blk >> 8;
    const int t2 = blk & 255;
    const int x0 = (t2 & 15) * TILE - HALO;
    const int y0 = (t2 >> 4) * TILE - HALO;
    const float* __restrict__ inp = in + (size_t)plane * (HH * WW);
    const float* __restrict__ tgp = tg + (size_t)plane * (HH * WW);

    // ---- copy taps into LDS (swizzled, pitch 64) ----
    for (int t = tid; t < 32 * 64; t += 256) {
        int r = t >> 6, k = t & 63;
        lds[G_O + r * 64 + SWZ(r, k)] = G[t];
    }

    // ---- stage 54 rows x 64 cols as bf16 pairs ----
    const bool interior = (x0 >= 0) && (y0 >= 0) && (x0 + 64 <= WW) && (y0 + 54 <= HH);
    if (interior) {
        // fast path: no bounds checks; task = 1 row x 8 cols, b128 LDS writes
        for (int t = tid; t < 54 * 8; t += 256) {
            int r = t >> 3, c8 = (t & 7) << 3;
            const float* pa = inp + (y0 + r) * WW + x0 + c8;
            const float* pb = tgp + (y0 + r) * WW + x0 + c8;
            uint4 va, vb;
            va.x = cvtpk(pa[0], pa[1]); va.y = cvtpk(pa[2], pa[3]);
            va.z = cvtpk(pa[4], pa[5]); va.w = cvtpk(pa[6], pa[7]);
            vb.x = cvtpk(pb[0], pb[1]); vb.y = cvtpk(pb[2], pb[3]);
            vb.z = cvtpk(pb[4], pb[5]); vb.w = cvtpk(pb[6], pb[7]);
            *(uint4*)&lds[SA_O + r * SPITCH + c8] = va;
            *(uint4*)&lds[SB_O + r * SPITCH + c8] = vb;
        }
    } else {
        unsigned* ldsw = (unsigned*)lds;
        for (int t = tid; t < 54 * 32; t += 256) {
            int r = t >> 5, cd = t & 31;
            int gy = y0 + r, gx = x0 + cd * 2;
            float a0 = 0.f, a1 = 0.f, b0 = 0.f, b1 = 0.f;
            if (gy >= 0 && gy < HH) {
                const float* ri = inp + gy * WW;
                const float* rt = tgp + gy * WW;
                if ((unsigned)gx < (unsigned)WW)       { a0 = ri[gx];     b0 = rt[gx]; }
                if ((unsigned)(gx + 1) < (unsigned)WW) { a1 = ri[gx + 1]; b1 = rt[gx + 1]; }
            }
            ldsw[(SA_O >> 1) + r * 36 + cd] = cvtpk(a0, a1);
            ldsw[(SB_O >> 1) + r * 36 + cd] = cvtpk(b0, b1);
        }
    }
    __syncthreads();

    // ---- h-pass (MFMA): wave = M-tile (image rows wave*16..+15) ----
    // hb[r][c] = sum_k S[r][k] * G[c][k]
    f32x4 acc5[5][2];
    const f32x4 zz = {0.f, 0.f, 0.f, 0.f};
    #pragma unroll
    for (int ch = 0; ch < 5; ++ch) { acc5[ch][0] = zz; acc5[ch][1] = zz; }

    #pragma unroll
    for (int ks = 0; ks < 2; ++ks) {
        const int off = (wave * 16 + m) * SPITCH + ks * 32 + q * 8;
        uint4 ua = *(const uint4*)&lds[SA_O + off];
        uint4 ub = *(const uint4*)&lds[SB_O + off];
        uint4 uaa = bfmul4(ua, ua);
        uint4 ubb = bfmul4(ub, ub);
        uint4 uab = bfmul4(ua, ub);
        #pragma unroll
        for (int nc = 0; nc < 2; ++nc) {
            const int gr = nc * 16 + m;
            uint4 gf = *(const uint4*)&lds[G_O + gr * 64 + SWZ(gr, ks * 32 + q * 8)];
            acc5[0][nc] = mfma16(ua,  gf, acc5[0][nc]);
            acc5[1][nc] = mfma16(ub,  gf, acc5[1][nc]);
            acc5[2][nc] = mfma16(uaa, gf, acc5[2][nc]);
            acc5[3][nc] = mfma16(ubb, gf, acc5[3][nc]);
            acc5[4][nc] = mfma16(uab, gf, acc5[4][nc]);
        }
    }
    // D frag: col = lane&15 (+nc*16), row = q*4 + reg (+wave*16). hbT[ch][col][row], bf16.
    #pragma unroll
    for (int ch = 0; ch < 5; ++ch)
        #pragma unroll
        for (int nc = 0; nc < 2; ++nc) {
            f32x4 a = acc5[ch][nc];
            uint2 pk;
            pk.x = cvtpk(a[0], a[1]);
            pk.y = cvtpk(a[2], a[3]);
            const int col = nc * 16 + m;
            const int rb = wave * 16 + q * 4;
            *(uint2*)&lds[HB_O + ch * HB_CH + col * 64 + SWZ(col, rb)] = pk;
        }
    __syncthreads();

    // ---- v-pass (MFMA): wave = output quadrant (mrow, nc2) ----
    // out[r][c] = sum_k G[r][k] * hb[k][c]; junk hb rows 54..63 hit G zeros.
    const int mrow = wave >> 1, nc2 = wave & 1;
    f32x4 av[5];
    #pragma unroll
    for (int ch = 0; ch < 5; ++ch) av[ch] = zz;

    #pragma unroll
    for (int ks = 0; ks < 2; ++ks) {
        const int ar = mrow * 16 + m;
        uint4 ga = *(const uint4*)&lds[G_O + ar * 64 + SWZ(ar, ks * 32 + q * 8)];
        #pragma unroll
        for (int ch = 0; ch < 5; ++ch) {
            const int col = nc2 * 16 + m;
            uint4 ub = *(const uint4*)&lds[HB_O + ch * HB_CH + col * 64 + SWZ(col, ks * 32 + q * 8)];
            av[ch] = mfma16(ga, ub, av[ch]);
        }
    }

    // ---- SSIM map on 4 px/lane + reduction ----
    float lsum = 0.f;
    #pragma unroll
    for (int i = 0; i < 4; ++i) {
        float vx = av[0][i], vt = av[1][i];
        float vxx = av[2][i], vtt = av[3][i], vxt = av[4][i];
        float m1s = vx * vx, m2s = vt * vt, m12 = vx * vt;
        float s1 = vxx - m1s, s2 = vtt - m2s, s12 = vxt - m12;
        float num = (2.f * m12 + C1V) * (2.f * s12 + C2V);
        float den = (m1s + m2s + C1V) * (s1 + s2 + C2V);
        lsum += num * __builtin_amdgcn_rcpf(den);   // den > 0 always
    }
    #pragma unroll
    for (int off = 32; off > 0; off >>= 1)
        lsum += __shfl_down(lsum, off, 64);
    if (lane == 0) swsum[wave] = lsum;
    __syncthreads();

    // ---- global accumulate; last block writes the loss ----
    if (tid == 0) {
        float s = swsum[0] + swsum[1] + swsum[2] + swsum[3];
        atomicAdd(acc, s);
        __threadfence();
        unsigned old = atomicAdd(cnt, 1u);
        if (old == (unsigned)(NBLK - 1)) {
            __threadfence();
            float tot = atomicAdd(acc, 0.0f);   // coherent read via RMW
            out[0] = 1.0f - tot * (1.0f / ((float)NPLANES * HH * WW));
        }
    }
}

extern "C" void kernel_launch(void* const* d_in, const int* in_sizes, int n_in,
                              void* d_out, int out_size, void* d_ws, size_t ws_size,
                              hipStream_t stream) {
    const float* inp = (const float*)d_in[0];
    const float* tgt = (const float*)d_in[1];
    const float* wgt = (const float*)d_in[2];
    float* out = (float*)d_out;
    float* acc = (float*)d_ws;                               // [0] fp32 sum
    unsigned* cnt = (unsigned*)d_ws + 1;                     // [1] block counter
    unsigned short* G = (unsigned short*)((char*)d_ws + 16); // 32*64 bf16 = 4 KB

    hipMemsetAsync(d_ws, 0, 16, stream);                     // zero acc + counter
    ssim_prep_kernel<<<1, 256, 0, stream>>>(wgt, G);
    ssim_main_kernel<<<NBLK, 256, 0, stream>>>(inp, tgt, G, acc, cnt, out);
}

// Round 10
// 271.277 us; speedup vs baseline: 3.6580x; 3.6580x over previous
//
#include <hip/hip_runtime.h>
#include <hip/hip_bf16.h>

typedef float f32x4 __attribute__((ext_vector_type(4)));
typedef short bf16x8 __attribute__((ext_vector_type(8)));

#define HH 512
#define WW 512
#define NPLANES 48              // B*C = 16*3
#define TILE 32
#define HALO 11
#define KSIZE 23
#define NBLK (16 * 16 * NPLANES)
#define C1V 1.0e-4f             // 0.01^2
#define C2V 9.0e-4f             // 0.03^2

// LDS layout (ushort indices). Overflow reads of padded M-rows (54..63):
// sB rows 54..63 -> sA rows 0..9 (finite staged bf16); sA rows 54..63 ->
// G region (finite bf16 taps). All junk multiplied by exact zeros in G.
#define SB_O   0                // 54 rows * 72
#define SA_O   3888             // 54 rows * 72
#define G_O    7776             // 32 rows * 64, xor-swizzled
#define HB_O   9824             // 5 ch * 32 cols * 64, xor-swizzled
#define HB_CH  2048
#define SPITCH 72               // staging pitch (16B-aligned rows, bank-spread)
#define LDS_TOT 20064           // 40128 B -> 4 blocks/CU

// XOR bank swizzle for pitch-64 regions; preserves 16B blocks (bits 0..2).
#define SWZ(rho, k) ((k) ^ (((rho) & 7) << 3))

__device__ __forceinline__ unsigned f2bf(float x) {   // fp32 -> bf16 bits (RNE)
    unsigned u = __float_as_uint(x);
    return (u + 0x7fffu + ((u >> 16) & 1u)) >> 16;
}

// pack two fp32 -> bf16 pair (lo = a, hi = b), RNE (v_cvt_pk_bf16_f32)
__device__ __forceinline__ unsigned cvtpk(float a, float b) {
    union { __hip_bfloat162 h; unsigned u; } cv;
    cv.h = __float22bfloat162_rn(make_float2(a, b));
    return cv.u;
}

// elementwise bf16 product of two bf16-pair dwords (fp32 exact mul, RNE round)
__device__ __forceinline__ unsigned bfmul2(unsigned a, unsigned b) {
    float al = __uint_as_float(a << 16), ah = __uint_as_float(a & 0xffff0000u);
    float bl = __uint_as_float(b << 16), bh = __uint_as_float(b & 0xffff0000u);
    return cvtpk(al * bl, ah * bh);
}

__device__ __forceinline__ uint4 bfmul4(uint4 a, uint4 b) {
    uint4 r;
    r.x = bfmul2(a.x, b.x); r.y = bfmul2(a.y, b.y);
    r.z = bfmul2(a.z, b.z); r.w = bfmul2(a.w, b.w);
    return r;
}

__device__ __forceinline__ f32x4 mfma16(uint4 a, uint4 b, f32x4 c) {
    union { uint4 u; bf16x8 h; } ua, ub;
    ua.u = a; ub.u = b;
    return __builtin_amdgcn_mfma_f32_16x16x32_bf16(ua.h, ub.h, c, 0, 0, 0);
}

__global__ __launch_bounds__(256, 4) void ssim_main_kernel(
    const float* __restrict__ in, const float* __restrict__ tg,
    const float* __restrict__ w, float* __restrict__ acc)
{
    __shared__ __align__(16) unsigned short lds[LDS_TOT];
    __shared__ float sg[KSIZE];
    __shared__ float swsum[4];

    const int tid = threadIdx.x;
    const int wave = tid >> 6, lane = tid & 63;
    const int m = lane & 15, q = lane >> 4;

    const int blk = blockIdx.x;
    const int plane = blk >> 8;
    const int t2 = blk & 255;
    const int x0 = (t2 & 15) * TILE - HALO;
    const int y0 = (t2 >> 4) * TILE - HALO;
    const float* __restrict__ inp = in + (size_t)plane * (HH * WW);
    const float* __restrict__ tgp = tg + (size_t)plane * (HH * WW);

    // ---- 1D taps = row sums of separable normalized 2D kernel (exact) ----
    if (tid < KSIZE) {
        float s = 0.f;
        #pragma unroll
        for (int k = 0; k < KSIZE; ++k) s += w[tid * KSIZE + k];
        sg[tid] = s;
    }
    __syncthreads();

    // ---- build G[32][64] in LDS (swizzled): G[r][k] = g[k-r] or 0 ----
    for (int t = tid; t < 32 * 64; t += 256) {
        int r = t >> 6, k = t & 63, d = k - r;
        unsigned short v = 0;
        if (d >= 0 && d < KSIZE) v = (unsigned short)f2bf(sg[d]);
        lds[G_O + r * 64 + SWZ(r, k)] = v;
    }

    // ---- stage 54 rows x 64 cols as bf16 pairs ----
    const bool interior = (x0 >= 0) && (y0 >= 0) && (x0 + 64 <= WW) && (y0 + 54 <= HH);
    if (interior) {
        // fast path: no bounds checks; task = 1 row x 8 cols, b128 LDS writes
        for (int t = tid; t < 54 * 8; t += 256) {
            int r = t >> 3, c8 = (t & 7) << 3;
            const float* pa = inp + (y0 + r) * WW + x0 + c8;
            const float* pb = tgp + (y0 + r) * WW + x0 + c8;
            uint4 va, vb;
            va.x = cvtpk(pa[0], pa[1]); va.y = cvtpk(pa[2], pa[3]);
            va.z = cvtpk(pa[4], pa[5]); va.w = cvtpk(pa[6], pa[7]);
            vb.x = cvtpk(pb[0], pb[1]); vb.y = cvtpk(pb[2], pb[3]);
            vb.z = cvtpk(pb[4], pb[5]); vb.w = cvtpk(pb[6], pb[7]);
            *(uint4*)&lds[SA_O + r * SPITCH + c8] = va;
            *(uint4*)&lds[SB_O + r * SPITCH + c8] = vb;
        }
    } else {
        unsigned* ldsw = (unsigned*)lds;
        for (int t = tid; t < 54 * 32; t += 256) {
            int r = t >> 5, cd = t & 31;
            int gy = y0 + r, gx = x0 + cd * 2;
            float a0 = 0.f, a1 = 0.f, b0 = 0.f, b1 = 0.f;
            if (gy >= 0 && gy < HH) {
                const float* ri = inp + gy * WW;
                const float* rt = tgp + gy * WW;
                if ((unsigned)gx < (unsigned)WW)       { a0 = ri[gx];     b0 = rt[gx]; }
                if ((unsigned)(gx + 1) < (unsigned)WW) { a1 = ri[gx + 1]; b1 = rt[gx + 1]; }
            }
            ldsw[(SA_O >> 1) + r * 36 + cd] = cvtpk(a0, a1);
            ldsw[(SB_O >> 1) + r * 36 + cd] = cvtpk(b0, b1);
        }
    }
    __syncthreads();

    // ---- h-pass (MFMA): wave = M-tile (image rows wave*16..+15) ----
    // hb[r][c] = sum_k S[r][k] * G[c][k]
    f32x4 acc5[5][2];
    const f32x4 zz = {0.f, 0.f, 0.f, 0.f};
    #pragma unroll
    for (int ch = 0; ch < 5; ++ch) { acc5[ch][0] = zz; acc5[ch][1] = zz; }

    #pragma unroll
    for (int ks = 0; ks < 2; ++ks) {
        const int off = (wave * 16 + m) * SPITCH + ks * 32 + q * 8;
        uint4 ua = *(const uint4*)&lds[SA_O + off];
        uint4 ub = *(const uint4*)&lds[SB_O + off];
        uint4 uaa = bfmul4(ua, ua);
        uint4 ubb = bfmul4(ub, ub);
        uint4 uab = bfmul4(ua, ub);
        #pragma unroll
        for (int nc = 0; nc < 2; ++nc) {
            const int gr = nc * 16 + m;
            uint4 gf = *(const uint4*)&lds[G_O + gr * 64 + SWZ(gr, ks * 32 + q * 8)];
            acc5[0][nc] = mfma16(ua,  gf, acc5[0][nc]);
            acc5[1][nc] = mfma16(ub,  gf, acc5[1][nc]);
            acc5[2][nc] = mfma16(uaa, gf, acc5[2][nc]);
            acc5[3][nc] = mfma16(ubb, gf, acc5[3][nc]);
            acc5[4][nc] = mfma16(uab, gf, acc5[4][nc]);
        }
    }
    // D frag: col = lane&15 (+nc*16), row = q*4 + reg (+wave*16). hbT[ch][col][row], bf16.
    #pragma unroll
    for (int ch = 0; ch < 5; ++ch)
        #pragma unroll
        for (int nc = 0; nc < 2; ++nc) {
            f32x4 a = acc5[ch][nc];
            uint2 pk;
            pk.x = cvtpk(a[0], a[1]);
            pk.y = cvtpk(a[2], a[3]);
            const int col = nc * 16 + m;
            const int rb = wave * 16 + q * 4;
            *(uint2*)&lds[HB_O + ch * HB_CH + col * 64 + SWZ(col, rb)] = pk;
        }
    __syncthreads();

    // ---- v-pass (MFMA): wave = output quadrant (mrow, nc2) ----
    // out[r][c] = sum_k G[r][k] * hb[k][c]; junk hb rows 54..63 hit G zeros.
    const int mrow = wave >> 1, nc2 = wave & 1;
    f32x4 av[5];
    #pragma unroll
    for (int ch = 0; ch < 5; ++ch) av[ch] = zz;

    #pragma unroll
    for (int ks = 0; ks < 2; ++ks) {
        const int ar = mrow * 16 + m;
        uint4 ga = *(const uint4*)&lds[G_O + ar * 64 + SWZ(ar, ks * 32 + q * 8)];
        #pragma unroll
        for (int ch = 0; ch < 5; ++ch) {
            const int col = nc2 * 16 + m;
            uint4 ub = *(const uint4*)&lds[HB_O + ch * HB_CH + col * 64 + SWZ(col, ks * 32 + q * 8)];
            av[ch] = mfma16(ga, ub, av[ch]);
        }
    }

    // ---- SSIM map on 4 px/lane + reduction ----
    float lsum = 0.f;
    #pragma unroll
    for (int i = 0; i < 4; ++i) {
        float vx = av[0][i], vt = av[1][i];
        float vxx = av[2][i], vtt = av[3][i], vxt = av[4][i];
        float m1s = vx * vx, m2s = vt * vt, m12 = vx * vt;
        float s1 = vxx - m1s, s2 = vtt - m2s, s12 = vxt - m12;
        float num = (2.f * m12 + C1V) * (2.f * s12 + C2V);
        float den = (m1s + m2s + C1V) * (s1 + s2 + C2V);
        lsum += num * __builtin_amdgcn_rcpf(den);   // den > 0 always
    }
    #pragma unroll
    for (int off = 32; off > 0; off >>= 1)
        lsum += __shfl_down(lsum, off, 64);
    if (lane == 0) swsum[wave] = lsum;
    __syncthreads();
    if (tid == 0)
        atomicAdd(acc, swsum[0] + swsum[1] + swsum[2] + swsum[3]);  // no fence: final kernel reads it
}

__global__ void ssim_final_kernel(const float* __restrict__ acc, float* __restrict__ out) {
    out[0] = 1.0f - acc[0] * (1.0f / ((float)NPLANES * HH * WW));
}

extern "C" void kernel_launch(void* const* d_in, const int* in_sizes, int n_in,
                              void* d_out, int out_size, void* d_ws, size_t ws_size,
                              hipStream_t stream) {
    const float* inp = (const float*)d_in[0];
    const float* tgt = (const float*)d_in[1];
    const float* wgt = (const float*)d_in[2];
    float* out = (float*)d_out;
    float* acc = (float*)d_ws;

    hipMemsetAsync(d_ws, 0, 4, stream);        // zero the accumulator
    ssim_main_kernel<<<NBLK, 256, 0, stream>>>(inp, tgt, wgt, acc);
    ssim_final_kernel<<<1, 1, 0, stream>>>(acc, out);
}

// Round 11
// 183.665 us; speedup vs baseline: 5.4029x; 1.4770x over previous
//
#include <hip/hip_runtime.h>
#include <hip/hip_bf16.h>

typedef float f32x4 __attribute__((ext_vector_type(4)));
typedef short bf16x8 __attribute__((ext_vector_type(8)));

#define HH 512
#define WW 512
#define NPLANES 48              // B*C = 16*3
#define TILE 32
#define HALO 11
#define KSIZE 23
#define NBLK (16 * 16 * NPLANES)
#define C1V 1.0e-4f             // 0.01^2
#define C2V 9.0e-4f             // 0.03^2

// LDS layout (ushort indices). Overflow reads of padded M-rows (54..63):
// sB rows 54..63 -> sA rows 0..9 (finite staged bf16); sA rows 54..63 ->
// G region (finite bf16 taps). All junk multiplied by exact zeros in G.
#define SB_O   0                // 54 rows * 72
#define SA_O   3888             // 54 rows * 72
#define G_O    7776             // 32 rows * 64, xor-swizzled
#define HB_O   9824             // 5 ch * 32 cols * 64, xor-swizzled
#define HB_CH  2048
#define SPITCH 72               // staging pitch (16B-aligned rows, bank-spread)
#define LDS_TOT 20064           // 40128 B -> 4 blocks/CU

// XOR bank swizzle for pitch-64 regions; preserves 16B blocks (bits 0..2).
#define SWZ(rho, k) ((k) ^ (((rho) & 7) << 3))

__device__ __forceinline__ unsigned f2bf(float x) {   // fp32 -> bf16 bits (RNE)
    unsigned u = __float_as_uint(x);
    return (u + 0x7fffu + ((u >> 16) & 1u)) >> 16;
}

// pack two fp32 -> bf16 pair (lo = a, hi = b), RNE (v_cvt_pk_bf16_f32)
__device__ __forceinline__ unsigned cvtpk(float a, float b) {
    union { __hip_bfloat162 h; unsigned u; } cv;
    cv.h = __float22bfloat162_rn(make_float2(a, b));
    return cv.u;
}

// elementwise bf16 product of two bf16-pair dwords (fp32 exact mul, RNE round)
__device__ __forceinline__ unsigned bfmul2(unsigned a, unsigned b) {
    float al = __uint_as_float(a << 16), ah = __uint_as_float(a & 0xffff0000u);
    float bl = __uint_as_float(b << 16), bh = __uint_as_float(b & 0xffff0000u);
    return cvtpk(al * bl, ah * bh);
}

__device__ __forceinline__ uint4 bfmul4(uint4 a, uint4 b) {
    uint4 r;
    r.x = bfmul2(a.x, b.x); r.y = bfmul2(a.y, b.y);
    r.z = bfmul2(a.z, b.z); r.w = bfmul2(a.w, b.w);
    return r;
}

__device__ __forceinline__ f32x4 mfma16(uint4 a, uint4 b, f32x4 c) {
    union { uint4 u; bf16x8 h; } ua, ub;
    ua.u = a; ub.u = b;
    return __builtin_amdgcn_mfma_f32_16x16x32_bf16(ua.h, ub.h, c, 0, 0, 0);
}

__global__ __launch_bounds__(256, 4) void ssim_main_kernel(
    const float* __restrict__ in, const float* __restrict__ tg,
    const float* __restrict__ w, float* __restrict__ partial)
{
    __shared__ __align__(16) unsigned short lds[LDS_TOT];
    __shared__ float sg[KSIZE];
    __shared__ float swsum[4];

    const int tid = threadIdx.x;
    const int wave = tid >> 6, lane = tid & 63;
    const int m = lane & 15, q = lane >> 4;

    const int blk = blockIdx.x;
    const int plane = blk >> 8;
    const int t2 = blk & 255;
    const int x0 = (t2 & 15) * TILE - HALO;
    const int y0 = (t2 >> 4) * TILE - HALO;
    const float* __restrict__ inp = in + (size_t)plane * (HH * WW);
    const float* __restrict__ tgp = tg + (size_t)plane * (HH * WW);

    // ---- 1D taps = row sums of separable normalized 2D kernel (exact) ----
    if (tid < KSIZE) {
        float s = 0.f;
        #pragma unroll
        for (int k = 0; k < KSIZE; ++k) s += w[tid * KSIZE + k];
        sg[tid] = s;
    }
    __syncthreads();

    // ---- build G[32][64] in LDS (swizzled): G[r][k] = g[k-r] or 0 ----
    for (int t = tid; t < 32 * 64; t += 256) {
        int r = t >> 6, k = t & 63, d = k - r;
        unsigned short v = 0;
        if (d >= 0 && d < KSIZE) v = (unsigned short)f2bf(sg[d]);
        lds[G_O + r * 64 + SWZ(r, k)] = v;
    }

    // ---- stage 54 rows x 64 cols as bf16 pairs ----
    const bool interior = (x0 >= 0) && (y0 >= 0) && (x0 + 64 <= WW) && (y0 + 54 <= HH);
    if (interior) {
        // fast path: no bounds checks; task = 1 row x 8 cols, b128 LDS writes
        for (int t = tid; t < 54 * 8; t += 256) {
            int r = t >> 3, c8 = (t & 7) << 3;
            const float* pa = inp + (y0 + r) * WW + x0 + c8;
            const float* pb = tgp + (y0 + r) * WW + x0 + c8;
            uint4 va, vb;
            va.x = cvtpk(pa[0], pa[1]); va.y = cvtpk(pa[2], pa[3]);
            va.z = cvtpk(pa[4], pa[5]); va.w = cvtpk(pa[6], pa[7]);
            vb.x = cvtpk(pb[0], pb[1]); vb.y = cvtpk(pb[2], pb[3]);
            vb.z = cvtpk(pb[4], pb[5]); vb.w = cvtpk(pb[6], pb[7]);
            *(uint4*)&lds[SA_O + r * SPITCH + c8] = va;
            *(uint4*)&lds[SB_O + r * SPITCH + c8] = vb;
        }
    } else {
        unsigned* ldsw = (unsigned*)lds;
        for (int t = tid; t < 54 * 32; t += 256) {
            int r = t >> 5, cd = t & 31;
            int gy = y0 + r, gx = x0 + cd * 2;
            float a0 = 0.f, a1 = 0.f, b0 = 0.f, b1 = 0.f;
            if (gy >= 0 && gy < HH) {
                const float* ri = inp + gy * WW;
                const float* rt = tgp + gy * WW;
                if ((unsigned)gx < (unsigned)WW)       { a0 = ri[gx];     b0 = rt[gx]; }
                if ((unsigned)(gx + 1) < (unsigned)WW) { a1 = ri[gx + 1]; b1 = rt[gx + 1]; }
            }
            ldsw[(SA_O >> 1) + r * 36 + cd] = cvtpk(a0, a1);
            ldsw[(SB_O >> 1) + r * 36 + cd] = cvtpk(b0, b1);
        }
    }
    __syncthreads();

    // ---- h-pass (MFMA): wave = M-tile (image rows wave*16..+15) ----
    // hb[r][c] = sum_k S[r][k] * G[c][k]
    f32x4 acc5[5][2];
    const f32x4 zz = {0.f, 0.f, 0.f, 0.f};
    #pragma unroll
    for (int ch = 0; ch < 5; ++ch) { acc5[ch][0] = zz; acc5[ch][1] = zz; }

    #pragma unroll
    for (int ks = 0; ks < 2; ++ks) {
        const int off = (wave * 16 + m) * SPITCH + ks * 32 + q * 8;
        uint4 ua = *(const uint4*)&lds[SA_O + off];
        uint4 ub = *(const uint4*)&lds[SB_O + off];
        uint4 uaa = bfmul4(ua, ua);
        uint4 ubb = bfmul4(ub, ub);
        uint4 uab = bfmul4(ua, ub);
        #pragma unroll
        for (int nc = 0; nc < 2; ++nc) {
            const int gr = nc * 16 + m;
            uint4 gf = *(const uint4*)&lds[G_O + gr * 64 + SWZ(gr, ks * 32 + q * 8)];
            acc5[0][nc] = mfma16(ua,  gf, acc5[0][nc]);
            acc5[1][nc] = mfma16(ub,  gf, acc5[1][nc]);
            acc5[2][nc] = mfma16(uaa, gf, acc5[2][nc]);
            acc5[3][nc] = mfma16(ubb, gf, acc5[3][nc]);
            acc5[4][nc] = mfma16(uab, gf, acc5[4][nc]);
        }
    }
    // D frag: col = lane&15 (+nc*16), row = q*4 + reg (+wave*16). hbT[ch][col][row], bf16.
    #pragma unroll
    for (int ch = 0; ch < 5; ++ch)
        #pragma unroll
        for (int nc = 0; nc < 2; ++nc) {
            f32x4 a = acc5[ch][nc];
            uint2 pk;
            pk.x = cvtpk(a[0], a[1]);
            pk.y = cvtpk(a[2], a[3]);
            const int col = nc * 16 + m;
            const int rb = wave * 16 + q * 4;
            *(uint2*)&lds[HB_O + ch * HB_CH + col * 64 + SWZ(col, rb)] = pk;
        }
    __syncthreads();

    // ---- v-pass (MFMA): wave = output quadrant (mrow, nc2) ----
    // out[r][c] = sum_k G[r][k] * hb[k][c]; junk hb rows 54..63 hit G zeros.
    const int mrow = wave >> 1, nc2 = wave & 1;
    f32x4 av[5];
    #pragma unroll
    for (int ch = 0; ch < 5; ++ch) av[ch] = zz;

    #pragma unroll
    for (int ks = 0; ks < 2; ++ks) {
        const int ar = mrow * 16 + m;
        uint4 ga = *(const uint4*)&lds[G_O + ar * 64 + SWZ(ar, ks * 32 + q * 8)];
        #pragma unroll
        for (int ch = 0; ch < 5; ++ch) {
            const int col = nc2 * 16 + m;
            uint4 ub = *(const uint4*)&lds[HB_O + ch * HB_CH + col * 64 + SWZ(col, ks * 32 + q * 8)];
            av[ch] = mfma16(ga, ub, av[ch]);
        }
    }

    // ---- SSIM map on 4 px/lane + reduction ----
    float lsum = 0.f;
    #pragma unroll
    for (int i = 0; i < 4; ++i) {
        float vx = av[0][i], vt = av[1][i];
        float vxx = av[2][i], vtt = av[3][i], vxt = av[4][i];
        float m1s = vx * vx, m2s = vt * vt, m12 = vx * vt;
        float s1 = vxx - m1s, s2 = vtt - m2s, s12 = vxt - m12;
        float num = (2.f * m12 + C1V) * (2.f * s12 + C2V);
        float den = (m1s + m2s + C1V) * (s1 + s2 + C2V);
        lsum += num * __builtin_amdgcn_rcpf(den);   // den > 0 always
    }
    #pragma unroll
    for (int off = 32; off > 0; off >>= 1)
        lsum += __shfl_down(lsum, off, 64);
    if (lane == 0) swsum[wave] = lsum;
    __syncthreads();
    if (tid == 0)
        partial[blk] = swsum[0] + swsum[1] + swsum[2] + swsum[3];  // plain store — no atomic, no fence
}

__global__ __launch_bounds__(256) void ssim_final_kernel(
    const float* __restrict__ partial, float* __restrict__ out)
{
    __shared__ float swsum[4];
    const int tid = threadIdx.x;
    float s = 0.f;
    // NBLK = 12288 floats = 3072 float4, grid-stride over 256 threads
    const float4* p4 = (const float4*)partial;
    for (int i = tid; i < NBLK / 4; i += 256) {
        float4 v = p4[i];
        s += (v.x + v.y) + (v.z + v.w);
    }
    #pragma unroll
    for (int off = 32; off > 0; off >>= 1)
        s += __shfl_down(s, off, 64);
    if ((tid & 63) == 0) swsum[tid >> 6] = s;
    __syncthreads();
    if (tid == 0)
        out[0] = 1.0f - (swsum[0] + swsum[1] + swsum[2] + swsum[3])
                        * (1.0f / ((float)NPLANES * HH * WW));
}

extern "C" void kernel_launch(void* const* d_in, const int* in_sizes, int n_in,
                              void* d_out, int out_size, void* d_ws, size_t ws_size,
                              hipStream_t stream) {
    const float* inp = (const float*)d_in[0];
    const float* tgt = (const float*)d_in[1];
    const float* wgt = (const float*)d_in[2];
    float* out = (float*)d_out;
    float* partial = (float*)d_ws;     // NBLK floats, fully overwritten each call

    ssim_main_kernel<<<NBLK, 256, 0, stream>>>(inp, tgt, wgt, partial);
    ssim_final_kernel<<<1, 256, 0, stream>>>(partial, out);
}